// Round 4
// baseline (87.433 us; speedup 1.0000x reference)
//
#include <hip/hip_runtime.h>

#define TPB 256
#define PTS 4          // query points per thread (2 x float2)
#define CHUNK 256      // database points staged per block (4 KB LDS)

typedef float f2 __attribute__((ext_vector_type(2)));

// ws layout: part[bz][group][mx] floats, bz = b*2+dir  (4 MB for B=2, G=32, mx=8192)

__global__ __launch_bounds__(TPB, 4) void nn_min(
        const float* __restrict__ pos, const float* __restrict__ xhat,
        float* __restrict__ part, int N, int M, int mx,
        float* __restrict__ out) {
    // zero the output accumulators (kernel boundary orders this before reduce_loss)
    if (blockIdx.x == 0 && blockIdx.y == 0 && blockIdx.z == 0 && threadIdx.x == 0) {
        out[0] = 0.0f; out[1] = 0.0f;
    }
    const int bz  = blockIdx.z;
    const int b   = bz >> 1;
    const int dir = bz & 1;
    // dir 0: queries = pos (N), database = xhat (M) -> dist1
    // dir 1: queries = xhat (M), database = pos (N) -> dist2
    const float* A  = dir ? xhat : pos;
    const float* Bp = dir ? pos  : xhat;
    const int NA = dir ? M : N;
    const int NB = dir ? N : M;
    const int G  = gridDim.y;
    float* outp = part + (size_t)(bz * G + blockIdx.y) * mx;

    // ---- stage database chunk with precomputed (-2bx,-2by,-2bz, |b|^2) ----
    __shared__ float4 sB[CHUNK];                 // 4 KB
    const int mbase = blockIdx.y * CHUNK;
    const int mlen  = min(CHUNK, NB - mbase);    // 256 for our sizes
    for (int j = threadIdx.x; j < mlen; j += TPB) {
        const float* p = Bp + (size_t)(b * NB + mbase + j) * 3;
        float x = p[0], y = p[1], z = p[2];
        sB[j] = make_float4(-2.0f * x, -2.0f * y, -2.0f * z,
                            x * x + y * y + z * z);
    }

    // ---- load query points into register float2 pairs ----
    const int i0 = blockIdx.x * (TPB * PTS) + threadIdx.x;
    f2 axv[2], ayv[2], azv[2], cav[2], mnv[2];
#pragma unroll
    for (int h = 0; h < 2; h++) {
#pragma unroll
        for (int u = 0; u < 2; u++) {
            int i  = i0 + (h * 2 + u) * TPB;
            int ic = i < NA ? i : NA - 1;        // clamp (no OOB read)
            const float* p = A + (size_t)(b * NA + ic) * 3;
            float x = p[0], y = p[1], z = p[2];
            axv[h][u] = x; ayv[h][u] = y; azv[h][u] = z;
            cav[h][u] = x * x + y * y + z * z;
            mnv[h][u] = 3.4e38f;
        }
    }
    __syncthreads();

    // ---- core: 4 db points/iter, pk-fma chains + v_min3 folds ----
    int j = 0;
    for (; j + 4 <= mlen; j += 4) {
        float4 q0 = sB[j];
        float4 q1 = sB[j + 1];
        float4 q2 = sB[j + 2];
        float4 q3 = sB[j + 3];
#pragma unroll
        for (int h = 0; h < 2; h++) {
            f2 s0 = axv[h] * q0.x + (ayv[h] * q0.y + (azv[h] * q0.z + q0.w));
            f2 s1 = axv[h] * q1.x + (ayv[h] * q1.y + (azv[h] * q1.z + q1.w));
            f2 s2 = axv[h] * q2.x + (ayv[h] * q2.y + (azv[h] * q2.z + q2.w));
            f2 s3 = axv[h] * q3.x + (ayv[h] * q3.y + (azv[h] * q3.z + q3.w));
#pragma unroll
            for (int u = 0; u < 2; u++) {
                mnv[h][u] = fminf(fminf(mnv[h][u], s0[u]), s1[u]);  // v_min3_f32
                mnv[h][u] = fminf(fminf(mnv[h][u], s2[u]), s3[u]);  // v_min3_f32
            }
        }
    }
    for (; j < mlen; ++j) {                      // tail (not hit at 256)
        float4 q = sB[j];
#pragma unroll
        for (int h = 0; h < 2; h++) {
            f2 s = axv[h] * q.x + (ayv[h] * q.y + (azv[h] * q.z + q.w));
            mnv[h][0] = fminf(mnv[h][0], s[0]);
            mnv[h][1] = fminf(mnv[h][1], s[1]);
        }
    }

    // ---- store partial min per (query, group): plain coalesced store ----
#pragma unroll
    for (int h = 0; h < 2; h++)
#pragma unroll
        for (int u = 0; u < 2; u++) {
            int i = i0 + (h * 2 + u) * TPB;
            if (i < NA)
                outp[i] = fmaxf(cav[h][u] + mnv[h][u], 0.0f);
        }
}

__global__ void reduce_loss(const float* __restrict__ part,
                            int N, int M, int mx, int G, int nbz,
                            float inv1, float inv2, float* __restrict__ out) {
    const int total  = nbz * mx;
    const int stride = gridDim.x * blockDim.x;
    float s = 0.0f;
    for (int t = blockIdx.x * blockDim.x + threadIdx.x; t < total; t += stride) {
        int bz = t / mx;
        int i  = t - bz * mx;
        int dir = bz & 1;
        int NA  = dir ? M : N;
        if (i < NA) {
            const float* p = part + (size_t)(bz * G) * mx + i;
            float mn = p[0];
            for (int g = 1; g < G; ++g)
                mn = fminf(mn, p[(size_t)g * mx]);
            s += mn * (dir ? inv2 : inv1);
        }
    }
    __shared__ float sh[TPB];
    sh[threadIdx.x] = s;
    __syncthreads();
    for (int off = TPB / 2; off > 0; off >>= 1) {
        if (threadIdx.x < off) sh[threadIdx.x] += sh[threadIdx.x + off];
        __syncthreads();
    }
    if (threadIdx.x == 0) {
        atomicAdd(&out[0], sh[0]);   // loss
        atomicAdd(&out[1], sh[0]);   // rec_loss (identical)
    }
}

extern "C" void kernel_launch(void* const* d_in, const int* in_sizes, int n_in,
                              void* d_out, int out_size, void* d_ws, size_t ws_size,
                              hipStream_t stream) {
    const float* pos  = (const float*)d_in[0];
    const float* xhat = (const float*)d_in[1];
    const int B = 2;
    const int N = in_sizes[0] / (B * 3);   // 8192
    const int M = in_sizes[1] / (B * 3);   // 8192
    float* out  = (float*)d_out;
    float* part = (float*)d_ws;

    const int mx    = N > M ? N : M;
    const int tiles = (mx + TPB * PTS - 1) / (TPB * PTS);  // 8
    const int G     = (mx + CHUNK - 1) / CHUNK;            // 32

    dim3 grid(tiles, G, B * 2);                            // 1024 blocks = 4/CU
    nn_min<<<grid, TPB, 0, stream>>>(pos, xhat, part, N, M, mx, out);

    reduce_loss<<<128, TPB, 0, stream>>>(part, N, M, mx, G, B * 2,
                                         1.0f / (B * N), 1.0f / (B * M), out);
}